// Round 1
// baseline (91.849 us; speedup 1.0000x reference)
//
#include <hip/hip_runtime.h>

#define NB 4096
#define HIST 200
#define NNEG 20
#define DIM 64
#define BATA 1e-4f
#define LAMDA 1e-4f

// one wave (64 lanes) per user; 4 waves / block
__global__ __launch_bounds__(256) void fism_kernel(
    const int* __restrict__ pos_items,
    const int* __restrict__ neg_items,
    const float* __restrict__ user_item_num,
    const int* __restrict__ interacted,
    const float* __restrict__ pu,
    const float* __restrict__ qi,
    const float* __restrict__ bi,
    float* __restrict__ out)
{
    const int wave = threadIdx.x >> 6;   // 0..3
    const int lane = threadIdx.x & 63;
    const int b    = blockIdx.x * 4 + wave;
    const int g    = lane >> 4;          // row-group 0..3
    const int c    = lane & 15;          // float4 column within a 64-f32 row

    __shared__ float s_dot[4][24];
    __shared__ float s_qsq[4][24];

    const float4* pu4 = (const float4*)pu;
    const float4* qi4 = (const float4*)qi;

    // ---- user embedding: sum of 200 pu rows; 4 rows per wave-iteration ----
    float4 u = make_float4(0.f, 0.f, 0.f, 0.f);
    const int* it = interacted + b * HIST;
    #pragma unroll 4
    for (int h = 0; h < HIST; h += 4) {
        int idx = it[h + g];                       // broadcast within group
        float4 v = pu4[idx * (DIM / 4) + c];       // coalesced 256B per group
        u.x += v.x; u.y += v.y; u.z += v.z; u.w += v.w;
    }
    // fold the 4 row-groups together (lanes sharing c hold the same dims)
    #pragma unroll
    for (int m = 16; m <= 32; m <<= 1) {
        u.x += __shfl_xor(u.x, m);
        u.y += __shfl_xor(u.y, m);
        u.z += __shfl_xor(u.z, m);
        u.w += __shfl_xor(u.w, m);
    }
    // u now holds dims [4c, 4c+3] of the user embedding, replicated 4x

    float contrib = 0.f;
    if (g == 0)   // count |u|^2 exactly once
        contrib += BATA * (u.x*u.x + u.y*u.y + u.z*u.z + u.w*u.w);

    // ---- 21 dot products: j==0 -> pos item, j>=1 -> neg item j-1 ----
    const int* negp = neg_items + b * NNEG;
    const int posi = pos_items[b];
    #pragma unroll
    for (int jj = 0; jj < 6; ++jj) {
        int j = jj * 4 + g;
        if (j < 21) {
            int item = (j == 0) ? posi : negp[j - 1];
            float4 q = qi4[item * (DIM / 4) + c];
            float dp = u.x*q.x + u.y*q.y + u.z*q.z + u.w*q.w;
            float qs = q.x*q.x + q.y*q.y + q.z*q.z + q.w*q.w;
            #pragma unroll
            for (int m = 1; m <= 8; m <<= 1) {     // reduce over the 16 lanes
                dp += __shfl_xor(dp, m);
                qs += __shfl_xor(qs, m);
            }
            if (c == 0) {
                s_dot[wave][j] = dp;
                s_qsq[wave][j] = qs;
            }
        }
    }
    __syncthreads();

    // ---- scores + loss terms ----
    const float t  = 1.0f / sqrtf(user_item_num[b]);   // num^(-0.5)
    const float bp = bi[posi];
    const float pos_score = t * s_dot[wave][0] + bp;

    if (lane < NNEG) {
        int nid = negp[lane];
        float bn = bi[nid];
        float neg_score = t * s_dot[wave][lane + 1] + bn;
        float d = 1.0f - pos_score + neg_score;
        contrib += d * d + LAMDA * bn * bn + BATA * s_qsq[wave][lane + 1];
    }
    if (lane == 0)
        contrib += LAMDA * bp * bp + BATA * s_qsq[wave][0];

    // ---- wave reduction + one atomic per wave ----
    #pragma unroll
    for (int m = 1; m < 64; m <<= 1)
        contrib += __shfl_xor(contrib, m);
    if (lane == 0)
        atomicAdd(out, contrib);
}

extern "C" void kernel_launch(void* const* d_in, const int* in_sizes, int n_in,
                              void* d_out, int out_size, void* d_ws, size_t ws_size,
                              hipStream_t stream) {
    const int*   pos_items     = (const int*)  d_in[0];
    const int*   neg_items     = (const int*)  d_in[1];
    const float* user_item_num = (const float*)d_in[2];
    const int*   interacted    = (const int*)  d_in[3];
    const float* pu            = (const float*)d_in[4];
    const float* qi            = (const float*)d_in[5];
    const float* bi            = (const float*)d_in[6];
    float* out = (float*)d_out;

    hipMemsetAsync(out, 0, sizeof(float), stream);   // d_out is poisoned; atomics accumulate
    fism_kernel<<<NB / 4, 256, 0, stream>>>(
        pos_items, neg_items, user_item_num, interacted, pu, qi, bi, out);
}

// Round 2
// 78.536 us; speedup vs baseline: 1.1695x; 1.1695x over previous
//
#include <hip/hip_runtime.h>

#define NB 4096
#define HIST 200
#define NNEG 20
#define DIM 64
#define BATA 1e-4f
#define LAMDA 1e-4f

// one BLOCK (4 waves, 256 threads) per user; 16 (wave,group) units split the
// 200-row history gather; 21 dots spread over the 16 units in 2 rounds.
__global__ __launch_bounds__(256) void fism_kernel(
    const int* __restrict__ pos_items,
    const int* __restrict__ neg_items,
    const float* __restrict__ user_item_num,
    const int* __restrict__ interacted,
    const float* __restrict__ pu,
    const float* __restrict__ qi,
    const float* __restrict__ bi,
    float* __restrict__ out)
{
    const int wave = threadIdx.x >> 6;   // 0..3
    const int lane = threadIdx.x & 63;
    const int g    = lane >> 4;          // row-group within wave, 0..3
    const int c    = lane & 15;          // float4 column within a 64-f32 row
    const int gid  = wave * 4 + g;       // 0..15 global group id
    const int b    = blockIdx.x;

    __shared__ float4 s_u[4][16];        // per-wave partial user embedding
    __shared__ float  s_dot[24];
    __shared__ float  s_qsq[24];

    const float4* pu4 = (const float4*)pu;
    const float4* qi4 = (const float4*)qi;
    const int*    it  = interacted + b * HIST;

    // ---- user embedding: 16 groups x 12 rows + 8-row tail ----
    float4 u = make_float4(0.f, 0.f, 0.f, 0.f);
    const int base = gid * 12;
    #pragma unroll 6
    for (int k = 0; k < 12; ++k) {
        int idx = it[base + k];                    // uniform within group
        float4 v = pu4[idx * (DIM / 4) + c];       // 256B per group, coalesced
        u.x += v.x; u.y += v.y; u.z += v.z; u.w += v.w;
    }
    if (gid < 8) {                                 // rows 192..199
        int idx = it[192 + gid];
        float4 v = pu4[idx * (DIM / 4) + c];
        u.x += v.x; u.y += v.y; u.z += v.z; u.w += v.w;
    }
    // fold the 4 groups within this wave (lanes sharing c hold same dims)
    #pragma unroll
    for (int m = 16; m <= 32; m <<= 1) {
        u.x += __shfl_xor(u.x, m);
        u.y += __shfl_xor(u.y, m);
        u.z += __shfl_xor(u.z, m);
        u.w += __shfl_xor(u.w, m);
    }
    if (lane < 16) s_u[wave][lane] = u;
    __syncthreads();

    // total user embedding, dims [4c, 4c+3]
    float4 u0 = s_u[0][c], u1 = s_u[1][c], u2 = s_u[2][c], u3 = s_u[3][c];
    float4 ut = make_float4(u0.x + u1.x + u2.x + u3.x,
                            u0.y + u1.y + u2.y + u3.y,
                            u0.z + u1.z + u2.z + u3.z,
                            u0.w + u1.w + u2.w + u3.w);

    float contrib = 0.f;
    if (wave == 0 && g == 0)   // 16 lanes cover the 16 columns exactly once
        contrib += BATA * (ut.x*ut.x + ut.y*ut.y + ut.z*ut.z + ut.w*ut.w);

    // ---- 21 dots: j==0 -> pos, j>=1 -> neg j-1; 16 groups x 2 rounds ----
    const int* negp = neg_items + b * NNEG;
    const int posi = pos_items[b];
    #pragma unroll
    for (int r = 0; r < 2; ++r) {
        int j = gid + 16 * r;
        if (j < 21) {
            int item = (j == 0) ? posi : negp[j - 1];
            float4 q = qi4[item * (DIM / 4) + c];
            float dp = ut.x*q.x + ut.y*q.y + ut.z*q.z + ut.w*q.w;
            float qs = q.x*q.x + q.y*q.y + q.z*q.z + q.w*q.w;
            #pragma unroll
            for (int m = 1; m <= 8; m <<= 1) {     // reduce over 16 lanes
                dp += __shfl_xor(dp, m);
                qs += __shfl_xor(qs, m);
            }
            if (c == 0) {
                s_dot[j] = dp;
                s_qsq[j] = qs;
            }
        }
    }
    __syncthreads();

    // ---- scores + loss terms (wave 0 only) ----
    if (wave == 0) {
        const float t  = 1.0f / sqrtf(user_item_num[b]);   // num^(-0.5)
        const float bp = bi[posi];
        const float pos_score = t * s_dot[0] + bp;

        if (lane < NNEG) {
            int nid = negp[lane];
            float bn = bi[nid];
            float neg_score = t * s_dot[lane + 1] + bn;
            float d = 1.0f - pos_score + neg_score;
            contrib += d * d + LAMDA * bn * bn + BATA * s_qsq[lane + 1];
        }
        if (lane == 0)
            contrib += LAMDA * bp * bp + BATA * s_qsq[0];

        #pragma unroll
        for (int m = 1; m < 64; m <<= 1)
            contrib += __shfl_xor(contrib, m);
        if (lane == 0)
            atomicAdd(out, contrib);
    }
}

extern "C" void kernel_launch(void* const* d_in, const int* in_sizes, int n_in,
                              void* d_out, int out_size, void* d_ws, size_t ws_size,
                              hipStream_t stream) {
    const int*   pos_items     = (const int*)  d_in[0];
    const int*   neg_items     = (const int*)  d_in[1];
    const float* user_item_num = (const float*)d_in[2];
    const int*   interacted    = (const int*)  d_in[3];
    const float* pu            = (const float*)d_in[4];
    const float* qi            = (const float*)d_in[5];
    const float* bi            = (const float*)d_in[6];
    float* out = (float*)d_out;

    hipMemsetAsync(out, 0, sizeof(float), stream);   // d_out is poisoned; atomics accumulate
    fism_kernel<<<NB, 256, 0, stream>>>(
        pos_items, neg_items, user_item_num, interacted, pu, qi, bi, out);
}

// Round 3
// 39.191 us; speedup vs baseline: 2.3436x; 2.0039x over previous
//
#include <hip/hip_runtime.h>

#define NB 4096
#define HIST 200
#define NNEG 20
#define DIM 64
#define BATA 1e-4f
#define LAMDA 1e-4f

// one BLOCK (4 waves, 256 threads) per user; 16 (wave,group) units split the
// 200-row history gather; 21 dots spread over the 16 units in 2 rounds.
// Partial losses land in d_ws[b]; a second 1-block kernel does the final sum
// (fixed order -> deterministic), replacing 4096 same-address atomicAdds.
__global__ __launch_bounds__(256) void fism_kernel(
    const int* __restrict__ pos_items,
    const int* __restrict__ neg_items,
    const float* __restrict__ user_item_num,
    const int* __restrict__ interacted,
    const float* __restrict__ pu,
    const float* __restrict__ qi,
    const float* __restrict__ bi,
    float* __restrict__ partials)
{
    const int wave = threadIdx.x >> 6;   // 0..3
    const int lane = threadIdx.x & 63;
    const int g    = lane >> 4;          // row-group within wave, 0..3
    const int c    = lane & 15;          // float4 column within a 64-f32 row
    const int gid  = wave * 4 + g;       // 0..15 global group id
    const int b    = blockIdx.x;

    __shared__ float4 s_u[4][16];        // per-wave partial user embedding
    __shared__ float  s_dot[24];
    __shared__ float  s_qsq[24];

    const float4* pu4 = (const float4*)pu;
    const float4* qi4 = (const float4*)qi;
    const int*    it  = interacted + b * HIST;

    // ---- user embedding: 16 groups x 12 rows + 8-row tail ----
    float4 u = make_float4(0.f, 0.f, 0.f, 0.f);
    const int base = gid * 12;
    #pragma unroll 6
    for (int k = 0; k < 12; ++k) {
        int idx = it[base + k];                    // uniform within group
        float4 v = pu4[idx * (DIM / 4) + c];       // 256B per group, coalesced
        u.x += v.x; u.y += v.y; u.z += v.z; u.w += v.w;
    }
    if (gid < 8) {                                 // rows 192..199
        int idx = it[192 + gid];
        float4 v = pu4[idx * (DIM / 4) + c];
        u.x += v.x; u.y += v.y; u.z += v.z; u.w += v.w;
    }
    // fold the 4 groups within this wave (lanes sharing c hold same dims)
    #pragma unroll
    for (int m = 16; m <= 32; m <<= 1) {
        u.x += __shfl_xor(u.x, m);
        u.y += __shfl_xor(u.y, m);
        u.z += __shfl_xor(u.z, m);
        u.w += __shfl_xor(u.w, m);
    }
    if (lane < 16) s_u[wave][lane] = u;
    __syncthreads();

    // total user embedding, dims [4c, 4c+3]
    float4 u0 = s_u[0][c], u1 = s_u[1][c], u2 = s_u[2][c], u3 = s_u[3][c];
    float4 ut = make_float4(u0.x + u1.x + u2.x + u3.x,
                            u0.y + u1.y + u2.y + u3.y,
                            u0.z + u1.z + u2.z + u3.z,
                            u0.w + u1.w + u2.w + u3.w);

    float contrib = 0.f;
    if (wave == 0 && g == 0)   // 16 lanes cover the 16 columns exactly once
        contrib += BATA * (ut.x*ut.x + ut.y*ut.y + ut.z*ut.z + ut.w*ut.w);

    // ---- 21 dots: j==0 -> pos, j>=1 -> neg j-1; 16 groups x 2 rounds ----
    const int* negp = neg_items + b * NNEG;
    const int posi = pos_items[b];
    #pragma unroll
    for (int r = 0; r < 2; ++r) {
        int j = gid + 16 * r;
        if (j < 21) {
            int item = (j == 0) ? posi : negp[j - 1];
            float4 q = qi4[item * (DIM / 4) + c];
            float dp = ut.x*q.x + ut.y*q.y + ut.z*q.z + ut.w*q.w;
            float qs = q.x*q.x + q.y*q.y + q.z*q.z + q.w*q.w;
            #pragma unroll
            for (int m = 1; m <= 8; m <<= 1) {     // reduce over 16 lanes
                dp += __shfl_xor(dp, m);
                qs += __shfl_xor(qs, m);
            }
            if (c == 0) {
                s_dot[j] = dp;
                s_qsq[j] = qs;
            }
        }
    }
    __syncthreads();

    // ---- scores + loss terms (wave 0 only) ----
    if (wave == 0) {
        const float t  = 1.0f / sqrtf(user_item_num[b]);   // num^(-0.5)
        const float bp = bi[posi];
        const float pos_score = t * s_dot[0] + bp;

        if (lane < NNEG) {
            int nid = negp[lane];
            float bn = bi[nid];
            float neg_score = t * s_dot[lane + 1] + bn;
            float d = 1.0f - pos_score + neg_score;
            contrib += d * d + LAMDA * bn * bn + BATA * s_qsq[lane + 1];
        }
        if (lane == 0)
            contrib += LAMDA * bp * bp + BATA * s_qsq[0];

        #pragma unroll
        for (int m = 1; m < 64; m <<= 1)
            contrib += __shfl_xor(contrib, m);
        if (lane == 0)
            partials[b] = contrib;               // plain store, no atomic
    }
}

// single block: sum 4096 partials in a fixed order -> out[0]
__global__ __launch_bounds__(1024) void reduce_kernel(
    const float* __restrict__ part, float* __restrict__ out)
{
    __shared__ float s[16];
    const int t = threadIdx.x;
    float v = 0.f;
    #pragma unroll
    for (int k = 0; k < NB / 1024; ++k)
        v += part[t + k * 1024];
    #pragma unroll
    for (int m = 1; m < 64; m <<= 1)
        v += __shfl_xor(v, m);
    if ((t & 63) == 0) s[t >> 6] = v;
    __syncthreads();
    if (t < 16) {
        float x = s[t];
        #pragma unroll
        for (int m = 1; m < 16; m <<= 1)
            x += __shfl_xor(x, m);
        if (t == 0) out[0] = x;
    }
}

extern "C" void kernel_launch(void* const* d_in, const int* in_sizes, int n_in,
                              void* d_out, int out_size, void* d_ws, size_t ws_size,
                              hipStream_t stream) {
    const int*   pos_items     = (const int*)  d_in[0];
    const int*   neg_items     = (const int*)  d_in[1];
    const float* user_item_num = (const float*)d_in[2];
    const int*   interacted    = (const int*)  d_in[3];
    const float* pu            = (const float*)d_in[4];
    const float* qi            = (const float*)d_in[5];
    const float* bi            = (const float*)d_in[6];
    float* partials = (float*)d_ws;               // 4096 floats = 16 KB
    float* out = (float*)d_out;

    fism_kernel<<<NB, 256, 0, stream>>>(
        pos_items, neg_items, user_item_num, interacted, pu, qi, bi, partials);
    reduce_kernel<<<1, 1024, 0, stream>>>(partials, out);
}

// Round 4
// 38.478 us; speedup vs baseline: 2.3870x; 1.0185x over previous
//
#include <hip/hip_runtime.h>

#define NB 4096
#define HIST 200
#define NNEG 20
#define DIM 64
#define BATA 1e-4f
#define LAMDA 1e-4f

// one BLOCK (4 waves) per user; 16 (wave,group) units x 12 rows + 8-row tail.
// All gather indices + qi fragments + biases preloaded up front so ~15
// independent loads are in flight per lane; partials -> d_ws, 1-block reduce.
__global__ __launch_bounds__(256) void fism_kernel(
    const int* __restrict__ pos_items,
    const int* __restrict__ neg_items,
    const float* __restrict__ user_item_num,
    const int* __restrict__ interacted,
    const float* __restrict__ pu,
    const float* __restrict__ qi,
    const float* __restrict__ bi,
    float* __restrict__ partials)
{
    const int wave = threadIdx.x >> 6;   // 0..3
    const int lane = threadIdx.x & 63;
    const int g    = lane >> 4;          // row-group within wave, 0..3
    const int c    = lane & 15;          // float4 column within a 64-f32 row
    const int gid  = wave * 4 + g;       // 0..15 global group id
    const int b    = blockIdx.x;

    __shared__ float4 s_u[4][16];
    __shared__ float  s_dot[24];
    __shared__ float  s_qsq[24];

    const float4* pu4 = (const float4*)pu;
    const float4* qi4 = (const float4*)qi;
    const int*    it  = interacted + b * HIST;
    const int*    negp = neg_items + b * NNEG;

    // ---- preload everything whose latency can hide under the pu gather ----
    const int posi = pos_items[b];

    // 12 contiguous history indices for this group (16B-aligned) + tail idx
    const int4* it4 = (const int4*)(it + gid * 12);
    int4 i0 = it4[0], i1 = it4[1], i2 = it4[2];
    int  tidx = it[192 + (gid & 7)];     // rows 192..199 (used by gid<8)

    // qi fragments for this group's dot products (j0 = gid, j1 = gid+16)
    const int item0 = (gid == 0) ? posi : negp[gid - 1];
    float4 q0 = qi4[item0 * (DIM / 4) + c];
    float4 q1 = make_float4(0.f, 0.f, 0.f, 0.f);
    if (gid < 5) {                       // j1 = gid+16 in [16,20]
        int item1 = negp[gid + 15];
        q1 = qi4[item1 * (DIM / 4) + c];
    }

    // wave-0 tail data
    float t_pow = 0.f, bp = 0.f, bn = 0.f;
    if (wave == 0) {
        t_pow = user_item_num[b];
        bp = bi[posi];
        if (lane < NNEG) bn = bi[negp[lane]];
    }

    // ---- user embedding: 13 independent row gathers, 2 accumulator chains --
    float4 a0 = make_float4(0.f, 0.f, 0.f, 0.f);
    float4 a1 = make_float4(0.f, 0.f, 0.f, 0.f);
    {
        float4 v0  = pu4[i0.x * (DIM / 4) + c];
        float4 v1  = pu4[i0.y * (DIM / 4) + c];
        float4 v2  = pu4[i0.z * (DIM / 4) + c];
        float4 v3  = pu4[i0.w * (DIM / 4) + c];
        float4 v4  = pu4[i1.x * (DIM / 4) + c];
        float4 v5  = pu4[i1.y * (DIM / 4) + c];
        float4 v6  = pu4[i1.z * (DIM / 4) + c];
        float4 v7  = pu4[i1.w * (DIM / 4) + c];
        float4 v8  = pu4[i2.x * (DIM / 4) + c];
        float4 v9  = pu4[i2.y * (DIM / 4) + c];
        float4 v10 = pu4[i2.z * (DIM / 4) + c];
        float4 v11 = pu4[i2.w * (DIM / 4) + c];
        float4 vt  = pu4[tidx * (DIM / 4) + c];

        a0.x += v0.x + v1.x; a0.y += v0.y + v1.y; a0.z += v0.z + v1.z; a0.w += v0.w + v1.w;
        a1.x += v2.x + v3.x; a1.y += v2.y + v3.y; a1.z += v2.z + v3.z; a1.w += v2.w + v3.w;
        a0.x += v4.x + v5.x; a0.y += v4.y + v5.y; a0.z += v4.z + v5.z; a0.w += v4.w + v5.w;
        a1.x += v6.x + v7.x; a1.y += v6.y + v7.y; a1.z += v6.z + v7.z; a1.w += v6.w + v7.w;
        a0.x += v8.x + v9.x; a0.y += v8.y + v9.y; a0.z += v8.z + v9.z; a0.w += v8.w + v9.w;
        a1.x += v10.x + v11.x; a1.y += v10.y + v11.y; a1.z += v10.z + v11.z; a1.w += v10.w + v11.w;
        if (gid < 8) {
            a0.x += vt.x; a0.y += vt.y; a0.z += vt.z; a0.w += vt.w;
        }
    }
    float4 u = make_float4(a0.x + a1.x, a0.y + a1.y, a0.z + a1.z, a0.w + a1.w);

    // fold the 4 groups within this wave (lanes sharing c hold same dims)
    #pragma unroll
    for (int m = 16; m <= 32; m <<= 1) {
        u.x += __shfl_xor(u.x, m);
        u.y += __shfl_xor(u.y, m);
        u.z += __shfl_xor(u.z, m);
        u.w += __shfl_xor(u.w, m);
    }
    if (lane < 16) s_u[wave][lane] = u;
    __syncthreads();

    // total user embedding, dims [4c, 4c+3]
    float4 u0 = s_u[0][c], u1 = s_u[1][c], u2 = s_u[2][c], u3 = s_u[3][c];
    float4 ut = make_float4(u0.x + u1.x + u2.x + u3.x,
                            u0.y + u1.y + u2.y + u3.y,
                            u0.z + u1.z + u2.z + u3.z,
                            u0.w + u1.w + u2.w + u3.w);

    float contrib = 0.f;
    if (wave == 0 && g == 0)   // 16 lanes cover the 16 columns exactly once
        contrib += BATA * (ut.x*ut.x + ut.y*ut.y + ut.z*ut.z + ut.w*ut.w);

    // ---- dots with preloaded qi fragments ----
    {
        float dp = ut.x*q0.x + ut.y*q0.y + ut.z*q0.z + ut.w*q0.w;
        float qs = q0.x*q0.x + q0.y*q0.y + q0.z*q0.z + q0.w*q0.w;
        #pragma unroll
        for (int m = 1; m <= 8; m <<= 1) {
            dp += __shfl_xor(dp, m);
            qs += __shfl_xor(qs, m);
        }
        if (c == 0) { s_dot[gid] = dp; s_qsq[gid] = qs; }
    }
    if (gid < 5) {
        float dp = ut.x*q1.x + ut.y*q1.y + ut.z*q1.z + ut.w*q1.w;
        float qs = q1.x*q1.x + q1.y*q1.y + q1.z*q1.z + q1.w*q1.w;
        #pragma unroll
        for (int m = 1; m <= 8; m <<= 1) {
            dp += __shfl_xor(dp, m);
            qs += __shfl_xor(qs, m);
        }
        if (c == 0) { s_dot[gid + 16] = dp; s_qsq[gid + 16] = qs; }
    }
    __syncthreads();

    // ---- scores + loss terms (wave 0 only) ----
    if (wave == 0) {
        const float t = 1.0f / sqrtf(t_pow);     // num^(-0.5)
        const float pos_score = t * s_dot[0] + bp;

        if (lane < NNEG) {
            float neg_score = t * s_dot[lane + 1] + bn;
            float d = 1.0f - pos_score + neg_score;
            contrib += d * d + LAMDA * bn * bn + BATA * s_qsq[lane + 1];
        }
        if (lane == 0)
            contrib += LAMDA * bp * bp + BATA * s_qsq[0];

        #pragma unroll
        for (int m = 1; m < 64; m <<= 1)
            contrib += __shfl_xor(contrib, m);
        if (lane == 0)
            partials[b] = contrib;               // plain store, no atomic
    }
}

// single block: sum 4096 partials in a fixed order -> out[0]
__global__ __launch_bounds__(1024) void reduce_kernel(
    const float* __restrict__ part, float* __restrict__ out)
{
    __shared__ float s[16];
    const int t = threadIdx.x;
    float v = 0.f;
    #pragma unroll
    for (int k = 0; k < NB / 1024; ++k)
        v += part[t + k * 1024];
    #pragma unroll
    for (int m = 1; m < 64; m <<= 1)
        v += __shfl_xor(v, m);
    if ((t & 63) == 0) s[t >> 6] = v;
    __syncthreads();
    if (t < 16) {
        float x = s[t];
        #pragma unroll
        for (int m = 1; m < 16; m <<= 1)
            x += __shfl_xor(x, m);
        if (t == 0) out[0] = x;
    }
}

extern "C" void kernel_launch(void* const* d_in, const int* in_sizes, int n_in,
                              void* d_out, int out_size, void* d_ws, size_t ws_size,
                              hipStream_t stream) {
    const int*   pos_items     = (const int*)  d_in[0];
    const int*   neg_items     = (const int*)  d_in[1];
    const float* user_item_num = (const float*)d_in[2];
    const int*   interacted    = (const int*)  d_in[3];
    const float* pu            = (const float*)d_in[4];
    const float* qi            = (const float*)d_in[5];
    const float* bi            = (const float*)d_in[6];
    float* partials = (float*)d_ws;               // 4096 floats = 16 KB
    float* out = (float*)d_out;

    fism_kernel<<<NB, 256, 0, stream>>>(
        pos_items, neg_items, user_item_num, interacted, pu, qi, bi, partials);
    reduce_kernel<<<1, 1024, 0, stream>>>(partials, out);
}